// Round 4
// baseline (602.821 us; speedup 1.0000x reference)
//
#include <hip/hip_runtime.h>

#define NN 50000
#define EE 800000
#define ETOT 850000
#define FIN 256
#define F1 128
#define F2 40

typedef unsigned int u32;
typedef unsigned short u16;

// fp32 -> bf16 (RNE), returned in low 16 bits
static __device__ __forceinline__ u32 f2bf(float f) {
  u32 u = __float_as_uint(f);
  return (u + 0x7FFFu + ((u >> 16) & 1u)) >> 16;
}

// ------- GEMM1 + fused attention dots: h1bf = bf16(x@W1); a_src1/a_dst1 -------
__global__ __launch_bounds__(256) void gemm1_kernel(const float* __restrict__ x,
                                                    const float* __restrict__ W1,
                                                    const float* __restrict__ att_src,
                                                    const float* __restrict__ att_dst,
                                                    u32* __restrict__ h1bf,
                                                    float* __restrict__ a_src,
                                                    float* __restrict__ a_dst) {
  __shared__ float Alds[16 * 68];
  __shared__ float Blds[16 * 128];
  __shared__ float att_s[128], att_d[128];
  const int t = threadIdx.x;
  if (t < 128) { att_s[t] = att_src[t]; att_d[t] = att_dst[t]; }
  const int tx = t & 15;
  const int ty = t >> 4;
  const int m0 = blockIdx.x * 64;
  const int arow = t >> 2;
  const int akk = (t & 3) * 4;
  const int brow = t >> 4;
  const int bc = (t & 15) * 4;

  float acc[4][8];
#pragma unroll
  for (int i = 0; i < 4; ++i)
#pragma unroll
    for (int j = 0; j < 8; ++j) acc[i][j] = 0.f;

  for (int k0 = 0; k0 < FIN; k0 += 16) {
    float4 av = {0.f, 0.f, 0.f, 0.f};
    int gr = m0 + arow;
    if (gr < NN) av = *(const float4*)(x + (size_t)gr * FIN + k0 + akk);
    float4 bv0 = *(const float4*)(W1 + (size_t)(k0 + brow) * F1 + bc);
    float4 bv1 = *(const float4*)(W1 + (size_t)(k0 + brow) * F1 + bc + 64);
    __syncthreads();
    Alds[(akk + 0) * 68 + arow] = av.x;
    Alds[(akk + 1) * 68 + arow] = av.y;
    Alds[(akk + 2) * 68 + arow] = av.z;
    Alds[(akk + 3) * 68 + arow] = av.w;
    *(float4*)(Blds + brow * 128 + bc) = bv0;
    *(float4*)(Blds + brow * 128 + bc + 64) = bv1;
    __syncthreads();
#pragma unroll
    for (int k = 0; k < 16; ++k) {
      float4 a4 = *(const float4*)(Alds + k * 68 + ty * 4);
      float4 b0 = *(const float4*)(Blds + k * 128 + tx * 4);
      float4 b1 = *(const float4*)(Blds + k * 128 + tx * 4 + 64);
      float aa[4] = {a4.x, a4.y, a4.z, a4.w};
      float bb[8] = {b0.x, b0.y, b0.z, b0.w, b1.x, b1.y, b1.z, b1.w};
#pragma unroll
      for (int i = 0; i < 4; ++i)
#pragma unroll
        for (int j = 0; j < 8; ++j) acc[i][j] = fmaf(aa[i], bb[j], acc[i][j]);
    }
  }
#pragma unroll
  for (int i = 0; i < 4; ++i) {
    int gr = m0 + ty * 4 + i;
    if (gr < NN) {
      uint2 w0, w1;
      w0.x = f2bf(acc[i][0]) | (f2bf(acc[i][1]) << 16);
      w0.y = f2bf(acc[i][2]) | (f2bf(acc[i][3]) << 16);
      w1.x = f2bf(acc[i][4]) | (f2bf(acc[i][5]) << 16);
      w1.y = f2bf(acc[i][6]) | (f2bf(acc[i][7]) << 16);
      *(uint2*)(h1bf + (size_t)gr * 64 + tx * 2) = w0;
      *(uint2*)(h1bf + (size_t)gr * 64 + 32 + tx * 2) = w1;
    }
  }
  // fused attention dots: reduce over the 8 lanes sharing (row, head-half)
#pragma unroll
  for (int i = 0; i < 4; ++i) {
    float ps = 0.f, pd = 0.f, ps2 = 0.f, pd2 = 0.f;
#pragma unroll
    for (int j = 0; j < 4; ++j) {
      int c = tx * 4 + j;
      ps  += acc[i][j]     * att_s[c];      pd  += acc[i][j]     * att_d[c];
      ps2 += acc[i][j + 4] * att_s[c + 64]; pd2 += acc[i][j + 4] * att_d[c + 64];
    }
#pragma unroll
    for (int off = 1; off < 8; off <<= 1) {
      ps  += __shfl_xor(ps, off);   pd  += __shfl_xor(pd, off);
      ps2 += __shfl_xor(ps2, off);  pd2 += __shfl_xor(pd2, off);
    }
    if ((tx & 7) == 0) {
      int gr = m0 + ty * 4 + i;
      if (gr < NN) {
        int hlo = tx >> 3;  // 0 or 1
        a_src[gr * 4 + hlo]     = ps;
        a_dst[gr * 4 + hlo]     = pd;
        a_src[gr * 4 + 2 + hlo] = ps2;
        a_dst[gr * 4 + 2 + hlo] = pd2;
      }
    }
  }
}

// ---------------- CSR build: degree histogram ----------------
__global__ __launch_bounds__(256) void deg_kernel(const int* __restrict__ ei,
                                                  int* __restrict__ deg) {
  int e = blockIdx.x * 256 + threadIdx.x;
  if (e >= ETOT) return;
  int dst = (e < EE) ? ei[EE + e] : (e - EE);
  atomicAdd(deg + dst, 1);
}

// ------- CSR build: exclusive scan, 2-phase chunk scan (single block) -------
__global__ __launch_bounds__(1024) void scan_kernel(const int* __restrict__ deg,
                                                    int* __restrict__ rowstart,
                                                    int* __restrict__ cursor) {
  __shared__ int part[1024];
  int t = threadIdx.x;
  const int C = (NN + 1023) / 1024;  // 49
  int lo = t * C;
  int hi = lo + C; if (hi > NN) hi = NN;
  if (lo > NN) lo = NN;
  int s = 0;
  for (int i = lo; i < hi; ++i) s += deg[i];
  part[t] = s;
  __syncthreads();
  for (int off = 1; off < 1024; off <<= 1) {
    int u = (t >= off) ? part[t - off] : 0;
    __syncthreads();
    part[t] += u;
    __syncthreads();
  }
  int run = part[t] - s;  // exclusive prefix of this chunk
  for (int i = lo; i < hi; ++i) {
    rowstart[i] = run;
    cursor[i] = run;
    run += deg[i];
  }
  if (t == 1023) rowstart[NN] = part[1023];
}

// ---------------- CSR build: scatter fill ----------------
__global__ __launch_bounds__(256) void fill_kernel(const int* __restrict__ ei,
                                                   int* __restrict__ cursor,
                                                   int* __restrict__ csr_src) {
  int e = blockIdx.x * 256 + threadIdx.x;
  if (e >= ETOT) return;
  int src, dst;
  if (e < EE) { src = ei[e]; dst = ei[EE + e]; }
  else        { src = e - EE; dst = src; }
  int pos = atomicAdd(cursor + dst, 1);
  csr_src[pos] = src;
}

// ------- gather layer1: pull aggregation over bf16 h1, 4 edges in flight -------
// 32 lanes per node; lane l: head=l>>3, feats l*4..l*4+3. 8 nodes per block.
__global__ __launch_bounds__(256) void gather1_kernel(const int* __restrict__ rowstart,
                                                      const int* __restrict__ csr_src,
                                                      const float* __restrict__ a_src,
                                                      const float* __restrict__ a_dst,
                                                      const u32* __restrict__ h1bf,
                                                      const float* __restrict__ b1,
                                                      float* __restrict__ h1b,
                                                      float* __restrict__ bnsum,
                                                      float* __restrict__ bnsq) {
  __shared__ float bns[128], bnq[128];
  int t = threadIdx.x;
  if (t < 128) { bns[t] = 0.f; bnq[t] = 0.f; }
  __syncthreads();
  int n = blockIdx.x * 8 + (t >> 5);   // grid = NN/8 exactly
  int l = t & 31;
  int head = l >> 3;
  int f0 = l * 4;
  float adst = a_dst[n * 4 + head];
  float acc0 = 0.f, acc1 = 0.f, acc2 = 0.f, acc3 = 0.f, ssum = 0.f;
  int beg = rowstart[n], end = rowstart[n + 1];
  int i = beg;
  for (; i + 3 < end; i += 4) {
    int s0 = csr_src[i + 0];
    int s1 = csr_src[i + 1];
    int s2 = csr_src[i + 2];
    int s3 = csr_src[i + 3];
    float e0 = a_src[s0 * 4 + head] + adst;
    float e1 = a_src[s1 * 4 + head] + adst;
    float e2 = a_src[s2 * 4 + head] + adst;
    float e3 = a_src[s3 * 4 + head] + adst;
    uint2 q0 = *(const uint2*)(h1bf + (size_t)s0 * 64 + l * 2);
    uint2 q1 = *(const uint2*)(h1bf + (size_t)s1 * 64 + l * 2);
    uint2 q2 = *(const uint2*)(h1bf + (size_t)s2 * 64 + l * 2);
    uint2 q3 = *(const uint2*)(h1bf + (size_t)s3 * 64 + l * 2);
    e0 = e0 > 0.f ? e0 : 0.2f * e0;  float x0 = __expf(e0);
    e1 = e1 > 0.f ? e1 : 0.2f * e1;  float x1 = __expf(e1);
    e2 = e2 > 0.f ? e2 : 0.2f * e2;  float x2 = __expf(e2);
    e3 = e3 > 0.f ? e3 : 0.2f * e3;  float x3 = __expf(e3);
    acc0 = fmaf(x0, __uint_as_float(q0.x << 16),        acc0);
    acc1 = fmaf(x0, __uint_as_float(q0.x & 0xFFFF0000u), acc1);
    acc2 = fmaf(x0, __uint_as_float(q0.y << 16),        acc2);
    acc3 = fmaf(x0, __uint_as_float(q0.y & 0xFFFF0000u), acc3);
    acc0 = fmaf(x1, __uint_as_float(q1.x << 16),        acc0);
    acc1 = fmaf(x1, __uint_as_float(q1.x & 0xFFFF0000u), acc1);
    acc2 = fmaf(x1, __uint_as_float(q1.y << 16),        acc2);
    acc3 = fmaf(x1, __uint_as_float(q1.y & 0xFFFF0000u), acc3);
    acc0 = fmaf(x2, __uint_as_float(q2.x << 16),        acc0);
    acc1 = fmaf(x2, __uint_as_float(q2.x & 0xFFFF0000u), acc1);
    acc2 = fmaf(x2, __uint_as_float(q2.y << 16),        acc2);
    acc3 = fmaf(x2, __uint_as_float(q2.y & 0xFFFF0000u), acc3);
    acc0 = fmaf(x3, __uint_as_float(q3.x << 16),        acc0);
    acc1 = fmaf(x3, __uint_as_float(q3.x & 0xFFFF0000u), acc1);
    acc2 = fmaf(x3, __uint_as_float(q3.y << 16),        acc2);
    acc3 = fmaf(x3, __uint_as_float(q3.y & 0xFFFF0000u), acc3);
    ssum += x0 + x1 + x2 + x3;
  }
  for (; i < end; ++i) {
    int s0 = csr_src[i];
    float e0 = a_src[s0 * 4 + head] + adst;
    e0 = e0 > 0.f ? e0 : 0.2f * e0;
    float x0 = __expf(e0);
    uint2 q0 = *(const uint2*)(h1bf + (size_t)s0 * 64 + l * 2);
    acc0 = fmaf(x0, __uint_as_float(q0.x << 16),        acc0);
    acc1 = fmaf(x0, __uint_as_float(q0.x & 0xFFFF0000u), acc1);
    acc2 = fmaf(x0, __uint_as_float(q0.y << 16),        acc2);
    acc3 = fmaf(x0, __uint_as_float(q0.y & 0xFFFF0000u), acc3);
    ssum += x0;
  }
  float inv = 1.f / (ssum + 1e-16f);
  float4 bb = *(const float4*)(b1 + f0);
  float4 o;
  o.x = acc0 * inv + bb.x;
  o.y = acc1 * inv + bb.y;
  o.z = acc2 * inv + bb.z;
  o.w = acc3 * inv + bb.w;
  *(float4*)(h1b + (size_t)n * F1 + f0) = o;
  atomicAdd(&bns[f0 + 0], o.x); atomicAdd(&bnq[f0 + 0], o.x * o.x);
  atomicAdd(&bns[f0 + 1], o.y); atomicAdd(&bnq[f0 + 1], o.y * o.y);
  atomicAdd(&bns[f0 + 2], o.z); atomicAdd(&bnq[f0 + 2], o.z * o.z);
  atomicAdd(&bns[f0 + 3], o.w); atomicAdd(&bnq[f0 + 3], o.w * o.w);
  __syncthreads();
  if (t < 128) {
    atomicAdd(bnsum + t, bns[t]);
    atomicAdd(bnsq + t, bnq[t]);
  }
}

// ---------------- BN stats -> per-feature scale/shift ----------------
__global__ void bnstats_kernel(const float* __restrict__ bnsum, const float* __restrict__ bnsq,
                               const float* __restrict__ gamma, const float* __restrict__ beta,
                               float* __restrict__ scale, float* __restrict__ shift) {
  int f = threadIdx.x;
  if (f < 128) {
    const float invN = 1.f / (float)NN;
    float mu = bnsum[f] * invN;
    float var = bnsq[f] * invN - mu * mu;
    float sc = gamma[f] * rsqrtf(var + 1e-5f);
    scale[f] = sc;
    shift[f] = beta[f] - mu * sc;
  }
}

// -- GEMM2 (BN+ELU fused on A-load, a2 dots fused): h2bf[N,64] bf16 padded --
__global__ __launch_bounds__(256) void gemm2_kernel(const float* __restrict__ hpre,
                                                    const float* __restrict__ W2,
                                                    const float* __restrict__ scale,
                                                    const float* __restrict__ shift,
                                                    const float* __restrict__ att_src2,
                                                    const float* __restrict__ att_dst2,
                                                    u16* __restrict__ h2bf,
                                                    float* __restrict__ a_src2,
                                                    float* __restrict__ a_dst2) {
  __shared__ float Wlds[128 * 40];
  __shared__ float Alds[16 * 128];
  __shared__ float sc[128], sh[128];
  int t = threadIdx.x;
  for (int i = t; i < 128 * 40; i += 256) Wlds[i] = W2[i];
  if (t < 128) { sc[t] = scale[t]; sh[t] = shift[t]; }
  int tr = t >> 3;
  int tc = t & 7;
  float as5[5], ad5[5];
#pragma unroll
  for (int j = 0; j < 5; ++j) { as5[j] = att_src2[tc * 5 + j]; ad5[j] = att_dst2[tc * 5 + j]; }
  int n0 = blockIdx.x * 128;
  int lrow = t >> 1;
  int lkk = (t & 1) * 8;
  float acc[4][5];
#pragma unroll
  for (int i = 0; i < 4; ++i)
#pragma unroll
    for (int j = 0; j < 5; ++j) acc[i][j] = 0.f;

  for (int k0 = 0; k0 < F1; k0 += 16) {
    float av[8];
    int gn = n0 + lrow;
    if (gn < NN) {
      float4 v0 = *(const float4*)(hpre + (size_t)gn * F1 + k0 + lkk);
      float4 v1 = *(const float4*)(hpre + (size_t)gn * F1 + k0 + lkk + 4);
      av[0] = v0.x; av[1] = v0.y; av[2] = v0.z; av[3] = v0.w;
      av[4] = v1.x; av[5] = v1.y; av[6] = v1.z; av[7] = v1.w;
    } else {
#pragma unroll
      for (int j = 0; j < 8; ++j) av[j] = 0.f;
    }
    __syncthreads();
#pragma unroll
    for (int j = 0; j < 8; ++j) {
      int kg = k0 + lkk + j;
      float a = av[j] * sc[kg] + sh[kg];
      a = a > 0.f ? a : (__expf(a) - 1.f);
      Alds[(lkk + j) * 128 + lrow] = a;
    }
    __syncthreads();
#pragma unroll
    for (int k = 0; k < 16; ++k) {
      float4 a4 = *(const float4*)(Alds + k * 128 + tr * 4);
      float aa[4] = {a4.x, a4.y, a4.z, a4.w};
      float w[5];
#pragma unroll
      for (int j = 0; j < 5; ++j) w[j] = Wlds[(k0 + k) * 40 + tc * 5 + j];
#pragma unroll
      for (int i = 0; i < 4; ++i)
#pragma unroll
        for (int j = 0; j < 5; ++j) acc[i][j] = fmaf(aa[i], w[j], acc[i][j]);
    }
  }
#pragma unroll
  for (int i = 0; i < 4; ++i) {
    int gn = n0 + tr * 4 + i;
    if (gn < NN) {
#pragma unroll
      for (int j = 0; j < 5; ++j)
        h2bf[(size_t)gn * 64 + tc * 5 + j] = (u16)f2bf(acc[i][j]);
      if (tc < 6) {
        uint2 z = {0u, 0u};
        *(uint2*)((u32*)h2bf + (size_t)gn * 32 + 20 + 2 * tc) = z;  // pad elems 40..63
      }
    }
  }
  // fused a2 dots: reduce across the 8 lanes (tc) sharing a row
#pragma unroll
  for (int i = 0; i < 4; ++i) {
    float ps = 0.f, pd = 0.f;
#pragma unroll
    for (int j = 0; j < 5; ++j) { ps += acc[i][j] * as5[j]; pd += acc[i][j] * ad5[j]; }
#pragma unroll
    for (int off = 1; off < 8; off <<= 1) {
      ps += __shfl_xor(ps, off);
      pd += __shfl_xor(pd, off);
    }
    if (tc == 0) {
      int gn = n0 + tr * 4 + i;
      if (gn < NN) { a_src2[gn] = ps; a_dst2[gn] = pd; }
    }
  }
}

// ------- gather layer2: pull over bf16 h2 (padded 64/row), writes output -------
// 8 lanes per node; lane l: feats l*8..l*8+7 (real feats < 40). 32 nodes/block.
__global__ __launch_bounds__(256) void gather2_kernel(const int* __restrict__ rowstart,
                                                      const int* __restrict__ csr_src,
                                                      const float* __restrict__ a_src,
                                                      const float* __restrict__ a_dst,
                                                      const u32* __restrict__ h2bf,
                                                      const float* __restrict__ b2,
                                                      float* __restrict__ out) {
  int t = threadIdx.x;
  int n = blockIdx.x * 32 + (t >> 3);
  if (n >= NN) return;
  int l = t & 7;
  float adst = a_dst[n];
  float acc[8] = {0.f, 0.f, 0.f, 0.f, 0.f, 0.f, 0.f, 0.f};
  float ssum = 0.f;
  int beg = rowstart[n], end = rowstart[n + 1];
  int i = beg;
  for (; i + 3 < end; i += 4) {
    int s0 = csr_src[i + 0];
    int s1 = csr_src[i + 1];
    int s2 = csr_src[i + 2];
    int s3 = csr_src[i + 3];
    float e0 = a_src[s0] + adst;
    float e1 = a_src[s1] + adst;
    float e2 = a_src[s2] + adst;
    float e3 = a_src[s3] + adst;
    uint4 q0 = *(const uint4*)(h2bf + (size_t)s0 * 32 + l * 4);
    uint4 q1 = *(const uint4*)(h2bf + (size_t)s1 * 32 + l * 4);
    uint4 q2 = *(const uint4*)(h2bf + (size_t)s2 * 32 + l * 4);
    uint4 q3 = *(const uint4*)(h2bf + (size_t)s3 * 32 + l * 4);
    e0 = e0 > 0.f ? e0 : 0.2f * e0;  float x0 = __expf(e0);
    e1 = e1 > 0.f ? e1 : 0.2f * e1;  float x1 = __expf(e1);
    e2 = e2 > 0.f ? e2 : 0.2f * e2;  float x2 = __expf(e2);
    e3 = e3 > 0.f ? e3 : 0.2f * e3;  float x3 = __expf(e3);
    u32 w[4];
    w[0] = q0.x; w[1] = q0.y; w[2] = q0.z; w[3] = q0.w;
#pragma unroll
    for (int j = 0; j < 4; ++j) {
      acc[2 * j]     = fmaf(x0, __uint_as_float(w[j] << 16),         acc[2 * j]);
      acc[2 * j + 1] = fmaf(x0, __uint_as_float(w[j] & 0xFFFF0000u), acc[2 * j + 1]);
    }
    w[0] = q1.x; w[1] = q1.y; w[2] = q1.z; w[3] = q1.w;
#pragma unroll
    for (int j = 0; j < 4; ++j) {
      acc[2 * j]     = fmaf(x1, __uint_as_float(w[j] << 16),         acc[2 * j]);
      acc[2 * j + 1] = fmaf(x1, __uint_as_float(w[j] & 0xFFFF0000u), acc[2 * j + 1]);
    }
    w[0] = q2.x; w[1] = q2.y; w[2] = q2.z; w[3] = q2.w;
#pragma unroll
    for (int j = 0; j < 4; ++j) {
      acc[2 * j]     = fmaf(x2, __uint_as_float(w[j] << 16),         acc[2 * j]);
      acc[2 * j + 1] = fmaf(x2, __uint_as_float(w[j] & 0xFFFF0000u), acc[2 * j + 1]);
    }
    w[0] = q3.x; w[1] = q3.y; w[2] = q3.z; w[3] = q3.w;
#pragma unroll
    for (int j = 0; j < 4; ++j) {
      acc[2 * j]     = fmaf(x3, __uint_as_float(w[j] << 16),         acc[2 * j]);
      acc[2 * j + 1] = fmaf(x3, __uint_as_float(w[j] & 0xFFFF0000u), acc[2 * j + 1]);
    }
    ssum += x0 + x1 + x2 + x3;
  }
  for (; i < end; ++i) {
    int s0 = csr_src[i];
    float e0 = a_src[s0] + adst;
    e0 = e0 > 0.f ? e0 : 0.2f * e0;
    float x0 = __expf(e0);
    uint4 q0 = *(const uint4*)(h2bf + (size_t)s0 * 32 + l * 4);
    u32 w[4];
    w[0] = q0.x; w[1] = q0.y; w[2] = q0.z; w[3] = q0.w;
#pragma unroll
    for (int j = 0; j < 4; ++j) {
      acc[2 * j]     = fmaf(x0, __uint_as_float(w[j] << 16),         acc[2 * j]);
      acc[2 * j + 1] = fmaf(x0, __uint_as_float(w[j] & 0xFFFF0000u), acc[2 * j + 1]);
    }
    ssum += x0;
  }
  float inv = 1.f / (ssum + 1e-16f);
  if (l < 5) {
    float* op = out + (size_t)n * F2 + l * 8;
#pragma unroll
    for (int j = 0; j < 8; ++j) op[j] = acc[j] * inv + b2[l * 8 + j];
  }
}

extern "C" void kernel_launch(void* const* d_in, const int* in_sizes, int n_in,
                              void* d_out, int out_size, void* d_ws, size_t ws_size,
                              hipStream_t stream) {
  const float* x        = (const float*)d_in[0];
  const int*   ei       = (const int*)d_in[1];
  const float* W1       = (const float*)d_in[2];
  const float* att_src1 = (const float*)d_in[3];
  const float* att_dst1 = (const float*)d_in[4];
  const float* b1       = (const float*)d_in[5];
  const float* gamma    = (const float*)d_in[6];
  const float* beta     = (const float*)d_in[7];
  const float* W2       = (const float*)d_in[8];
  const float* att_src2 = (const float*)d_in[9];
  const float* att_dst2 = (const float*)d_in[10];
  const float* b2       = (const float*)d_in[11];
  float* out = (float*)d_out;

  // ---- workspace layout (all element counts multiples of 4 -> 16B aligned) ----
  int* deg = (int*)d_ws;                       // 50048 (zeroed)
  float* bnsum = (float*)(deg + 50048);        // 128   (zeroed)
  float* bnsq  = bnsum + 128;                  // 128   (zeroed)
  int* rowstart = (int*)(bnsq + 128);          // 50004
  int* cursor   = rowstart + 50004;            // 50000
  int* csr_src  = cursor + 50000;              // 850000
  u32* h1bf     = (u32*)(csr_src + 850000);    // 50000*64 = 3,200,000 u32 (bf16 x2)
  float* h1b    = (float*)(h1bf + 3200000);    // 6,400,000
  u32* h2bf     = (u32*)(h1b + 6400000);       // 50000*32 = 1,600,000 u32 (bf16 x2)
  float* a_src1 = (float*)(h2bf + 1600000);    // 200000
  float* a_dst1 = a_src1 + 200000;             // 200000
  float* a_src2 = a_dst1 + 200000;             // 50000
  float* a_dst2 = a_src2 + 50000;              // 50000
  float* scale  = a_dst2 + 50000;              // 128
  float* shift  = scale + 128;                 // 128

  hipMemsetAsync(deg, 0, (50048 + 256) * sizeof(int), stream);

  deg_kernel<<<(ETOT + 255) / 256, 256, 0, stream>>>(ei, deg);
  scan_kernel<<<1, 1024, 0, stream>>>(deg, rowstart, cursor);
  fill_kernel<<<(ETOT + 255) / 256, 256, 0, stream>>>(ei, cursor, csr_src);

  gemm1_kernel<<<(NN + 63) / 64, 256, 0, stream>>>(x, W1, att_src1, att_dst1,
                                                   h1bf, a_src1, a_dst1);
  gather1_kernel<<<NN / 8, 256, 0, stream>>>(rowstart, csr_src, a_src1, a_dst1,
                                             h1bf, b1, h1b, bnsum, bnsq);
  bnstats_kernel<<<1, 128, 0, stream>>>(bnsum, bnsq, gamma, beta, scale, shift);
  gemm2_kernel<<<(NN + 127) / 128, 256, 0, stream>>>(h1b, W2, scale, shift,
                                                     att_src2, att_dst2,
                                                     (u16*)h2bf, a_src2, a_dst2);
  gather2_kernel<<<(NN + 31) / 32, 256, 0, stream>>>(rowstart, csr_src, a_src2, a_dst2,
                                                     h2bf, b2, out);
}

// Round 5
// 525.759 us; speedup vs baseline: 1.1466x; 1.1466x over previous
//
#include <hip/hip_runtime.h>

#define NN 50000
#define EE 800000
#define ETOT 850000
#define FIN 256
#define F1 128
#define F2 40

typedef unsigned int u32;
typedef unsigned short u16;

// fp32 -> bf16 (RNE), returned in low 16 bits
static __device__ __forceinline__ u32 f2bf(float f) {
  u32 u = __float_as_uint(f);
  return (u + 0x7FFFu + ((u >> 16) & 1u)) >> 16;
}
#define BF_LO(u) __uint_as_float((u) << 16)
#define BF_HI(u) __uint_as_float((u) & 0xFFFF0000u)

// ------- GEMM1 + fused attention dots: h1bf = bf16(x@W1); a_src1/a_dst1 -------
__global__ __launch_bounds__(256) void gemm1_kernel(const float* __restrict__ x,
                                                    const float* __restrict__ W1,
                                                    const float* __restrict__ att_src,
                                                    const float* __restrict__ att_dst,
                                                    u32* __restrict__ h1bf,
                                                    float* __restrict__ a_src,
                                                    float* __restrict__ a_dst) {
  __shared__ float Alds[16 * 68];
  __shared__ float Blds[16 * 128];
  __shared__ float att_s[128], att_d[128];
  const int t = threadIdx.x;
  if (t < 128) { att_s[t] = att_src[t]; att_d[t] = att_dst[t]; }
  const int tx = t & 15;
  const int ty = t >> 4;
  const int m0 = blockIdx.x * 64;
  const int arow = t >> 2;
  const int akk = (t & 3) * 4;
  const int brow = t >> 4;
  const int bc = (t & 15) * 4;

  float acc[4][8];
#pragma unroll
  for (int i = 0; i < 4; ++i)
#pragma unroll
    for (int j = 0; j < 8; ++j) acc[i][j] = 0.f;

  for (int k0 = 0; k0 < FIN; k0 += 16) {
    float4 av = {0.f, 0.f, 0.f, 0.f};
    int gr = m0 + arow;
    if (gr < NN) av = *(const float4*)(x + (size_t)gr * FIN + k0 + akk);
    float4 bv0 = *(const float4*)(W1 + (size_t)(k0 + brow) * F1 + bc);
    float4 bv1 = *(const float4*)(W1 + (size_t)(k0 + brow) * F1 + bc + 64);
    __syncthreads();
    Alds[(akk + 0) * 68 + arow] = av.x;
    Alds[(akk + 1) * 68 + arow] = av.y;
    Alds[(akk + 2) * 68 + arow] = av.z;
    Alds[(akk + 3) * 68 + arow] = av.w;
    *(float4*)(Blds + brow * 128 + bc) = bv0;
    *(float4*)(Blds + brow * 128 + bc + 64) = bv1;
    __syncthreads();
#pragma unroll
    for (int k = 0; k < 16; ++k) {
      float4 a4 = *(const float4*)(Alds + k * 68 + ty * 4);
      float4 b0 = *(const float4*)(Blds + k * 128 + tx * 4);
      float4 b1 = *(const float4*)(Blds + k * 128 + tx * 4 + 64);
      float aa[4] = {a4.x, a4.y, a4.z, a4.w};
      float bb[8] = {b0.x, b0.y, b0.z, b0.w, b1.x, b1.y, b1.z, b1.w};
#pragma unroll
      for (int i = 0; i < 4; ++i)
#pragma unroll
        for (int j = 0; j < 8; ++j) acc[i][j] = fmaf(aa[i], bb[j], acc[i][j]);
    }
  }
#pragma unroll
  for (int i = 0; i < 4; ++i) {
    int gr = m0 + ty * 4 + i;
    if (gr < NN) {
      uint2 w0, w1;
      w0.x = f2bf(acc[i][0]) | (f2bf(acc[i][1]) << 16);
      w0.y = f2bf(acc[i][2]) | (f2bf(acc[i][3]) << 16);
      w1.x = f2bf(acc[i][4]) | (f2bf(acc[i][5]) << 16);
      w1.y = f2bf(acc[i][6]) | (f2bf(acc[i][7]) << 16);
      *(uint2*)(h1bf + (size_t)gr * 64 + tx * 2) = w0;
      *(uint2*)(h1bf + (size_t)gr * 64 + 32 + tx * 2) = w1;
    }
  }
  // fused attention dots: reduce over the 8 lanes sharing (row, head-half)
#pragma unroll
  for (int i = 0; i < 4; ++i) {
    float ps = 0.f, pd = 0.f, ps2 = 0.f, pd2 = 0.f;
#pragma unroll
    for (int j = 0; j < 4; ++j) {
      int c = tx * 4 + j;
      ps  += acc[i][j]     * att_s[c];      pd  += acc[i][j]     * att_d[c];
      ps2 += acc[i][j + 4] * att_s[c + 64]; pd2 += acc[i][j + 4] * att_d[c + 64];
    }
#pragma unroll
    for (int off = 1; off < 8; off <<= 1) {
      ps  += __shfl_xor(ps, off);   pd  += __shfl_xor(pd, off);
      ps2 += __shfl_xor(ps2, off);  pd2 += __shfl_xor(pd2, off);
    }
    if ((tx & 7) == 0) {
      int gr = m0 + ty * 4 + i;
      if (gr < NN) {
        int hlo = tx >> 3;  // 0 or 1
        a_src[gr * 4 + hlo]     = ps;
        a_dst[gr * 4 + hlo]     = pd;
        a_src[gr * 4 + 2 + hlo] = ps2;
        a_dst[gr * 4 + 2 + hlo] = pd2;
      }
    }
  }
}

// ---------------- CSR build: degree histogram ----------------
__global__ __launch_bounds__(256) void deg_kernel(const int* __restrict__ ei,
                                                  int* __restrict__ deg) {
  int e = blockIdx.x * 256 + threadIdx.x;
  if (e >= ETOT) return;
  int dst = (e < EE) ? ei[EE + e] : (e - EE);
  atomicAdd(deg + dst, 1);
}

// ------- CSR build: exclusive scan, 2-phase chunk scan (single block) -------
__global__ __launch_bounds__(1024) void scan_kernel(const int* __restrict__ deg,
                                                    int* __restrict__ rowstart,
                                                    int* __restrict__ cursor) {
  __shared__ int part[1024];
  int t = threadIdx.x;
  const int C = (NN + 1023) / 1024;  // 49
  int lo = t * C;
  int hi = lo + C; if (hi > NN) hi = NN;
  if (lo > NN) lo = NN;
  int s = 0;
  for (int i = lo; i < hi; ++i) s += deg[i];
  part[t] = s;
  __syncthreads();
  for (int off = 1; off < 1024; off <<= 1) {
    int u = (t >= off) ? part[t - off] : 0;
    __syncthreads();
    part[t] += u;
    __syncthreads();
  }
  int run = part[t] - s;  // exclusive prefix of this chunk
  for (int i = lo; i < hi; ++i) {
    rowstart[i] = run;
    cursor[i] = run;
    run += deg[i];
  }
  if (t == 1023) rowstart[NN] = part[1023];
}

// ---------------- CSR build: scatter fill ----------------
__global__ __launch_bounds__(256) void fill_kernel(const int* __restrict__ ei,
                                                   int* __restrict__ cursor,
                                                   int* __restrict__ csr_src) {
  int e = blockIdx.x * 256 + threadIdx.x;
  if (e >= ETOT) return;
  int src, dst;
  if (e < EE) { src = ei[e]; dst = ei[EE + e]; }
  else        { src = e - EE; dst = src; }
  int pos = atomicAdd(cursor + dst, 1);
  csr_src[pos] = src;
}

// ------- gather layer1: 16 lanes/node, uint4 row loads, int4 csr loads -------
// lane l: head=l>>2, feats l*8..l*8+7. 16 nodes per block. grid = NN/16 exact.
__global__ __launch_bounds__(256) void gather1_kernel(const int* __restrict__ rowstart,
                                                      const int* __restrict__ csr_src,
                                                      const float* __restrict__ a_src,
                                                      const float* __restrict__ a_dst,
                                                      const u32* __restrict__ h1bf,
                                                      const float* __restrict__ b1,
                                                      float* __restrict__ h1b,
                                                      float* __restrict__ bnsum,
                                                      float* __restrict__ bnsq) {
  __shared__ float bns[128], bnq[128];
  int t = threadIdx.x;
  if (t < 128) { bns[t] = 0.f; bnq[t] = 0.f; }
  __syncthreads();
  int n = blockIdx.x * 16 + (t >> 4);
  int l = t & 15;
  int head = l >> 2;
  int f0 = l * 8;
  float adst = a_dst[n * 4 + head];
  float acc[8] = {0.f, 0.f, 0.f, 0.f, 0.f, 0.f, 0.f, 0.f};
  float ssum = 0.f;
  int beg = rowstart[n], end = rowstart[n + 1];
  int i = beg;
  // peel to 16B alignment of csr_src + i
  for (; i < end && (i & 3); ++i) {
    int s0 = csr_src[i];
    float e0 = a_src[s0 * 4 + head] + adst;
    e0 = e0 > 0.f ? e0 : 0.2f * e0;
    float x0 = __expf(e0);
    uint4 q = *(const uint4*)(h1bf + (size_t)s0 * 64 + l * 4);
    acc[0] = fmaf(x0, BF_LO(q.x), acc[0]); acc[1] = fmaf(x0, BF_HI(q.x), acc[1]);
    acc[2] = fmaf(x0, BF_LO(q.y), acc[2]); acc[3] = fmaf(x0, BF_HI(q.y), acc[3]);
    acc[4] = fmaf(x0, BF_LO(q.z), acc[4]); acc[5] = fmaf(x0, BF_HI(q.z), acc[5]);
    acc[6] = fmaf(x0, BF_LO(q.w), acc[6]); acc[7] = fmaf(x0, BF_HI(q.w), acc[7]);
    ssum += x0;
  }
  for (; i + 3 < end; i += 4) {
    int4 s4 = *(const int4*)(csr_src + i);
    float e0 = a_src[s4.x * 4 + head] + adst;
    float e1 = a_src[s4.y * 4 + head] + adst;
    float e2 = a_src[s4.z * 4 + head] + adst;
    float e3 = a_src[s4.w * 4 + head] + adst;
    uint4 q0 = *(const uint4*)(h1bf + (size_t)s4.x * 64 + l * 4);
    uint4 q1 = *(const uint4*)(h1bf + (size_t)s4.y * 64 + l * 4);
    uint4 q2 = *(const uint4*)(h1bf + (size_t)s4.z * 64 + l * 4);
    uint4 q3 = *(const uint4*)(h1bf + (size_t)s4.w * 64 + l * 4);
    e0 = e0 > 0.f ? e0 : 0.2f * e0;  float x0 = __expf(e0);
    e1 = e1 > 0.f ? e1 : 0.2f * e1;  float x1 = __expf(e1);
    e2 = e2 > 0.f ? e2 : 0.2f * e2;  float x2 = __expf(e2);
    e3 = e3 > 0.f ? e3 : 0.2f * e3;  float x3 = __expf(e3);
    acc[0] = fmaf(x0, BF_LO(q0.x), acc[0]); acc[1] = fmaf(x0, BF_HI(q0.x), acc[1]);
    acc[2] = fmaf(x0, BF_LO(q0.y), acc[2]); acc[3] = fmaf(x0, BF_HI(q0.y), acc[3]);
    acc[4] = fmaf(x0, BF_LO(q0.z), acc[4]); acc[5] = fmaf(x0, BF_HI(q0.z), acc[5]);
    acc[6] = fmaf(x0, BF_LO(q0.w), acc[6]); acc[7] = fmaf(x0, BF_HI(q0.w), acc[7]);
    acc[0] = fmaf(x1, BF_LO(q1.x), acc[0]); acc[1] = fmaf(x1, BF_HI(q1.x), acc[1]);
    acc[2] = fmaf(x1, BF_LO(q1.y), acc[2]); acc[3] = fmaf(x1, BF_HI(q1.y), acc[3]);
    acc[4] = fmaf(x1, BF_LO(q1.z), acc[4]); acc[5] = fmaf(x1, BF_HI(q1.z), acc[5]);
    acc[6] = fmaf(x1, BF_LO(q1.w), acc[6]); acc[7] = fmaf(x1, BF_HI(q1.w), acc[7]);
    acc[0] = fmaf(x2, BF_LO(q2.x), acc[0]); acc[1] = fmaf(x2, BF_HI(q2.x), acc[1]);
    acc[2] = fmaf(x2, BF_LO(q2.y), acc[2]); acc[3] = fmaf(x2, BF_HI(q2.y), acc[3]);
    acc[4] = fmaf(x2, BF_LO(q2.z), acc[4]); acc[5] = fmaf(x2, BF_HI(q2.z), acc[5]);
    acc[6] = fmaf(x2, BF_LO(q2.w), acc[6]); acc[7] = fmaf(x2, BF_HI(q2.w), acc[7]);
    acc[0] = fmaf(x3, BF_LO(q3.x), acc[0]); acc[1] = fmaf(x3, BF_HI(q3.x), acc[1]);
    acc[2] = fmaf(x3, BF_LO(q3.y), acc[2]); acc[3] = fmaf(x3, BF_HI(q3.y), acc[3]);
    acc[4] = fmaf(x3, BF_LO(q3.z), acc[4]); acc[5] = fmaf(x3, BF_HI(q3.z), acc[5]);
    acc[6] = fmaf(x3, BF_LO(q3.w), acc[6]); acc[7] = fmaf(x3, BF_HI(q3.w), acc[7]);
    ssum += x0 + x1 + x2 + x3;
  }
  for (; i < end; ++i) {
    int s0 = csr_src[i];
    float e0 = a_src[s0 * 4 + head] + adst;
    e0 = e0 > 0.f ? e0 : 0.2f * e0;
    float x0 = __expf(e0);
    uint4 q = *(const uint4*)(h1bf + (size_t)s0 * 64 + l * 4);
    acc[0] = fmaf(x0, BF_LO(q.x), acc[0]); acc[1] = fmaf(x0, BF_HI(q.x), acc[1]);
    acc[2] = fmaf(x0, BF_LO(q.y), acc[2]); acc[3] = fmaf(x0, BF_HI(q.y), acc[3]);
    acc[4] = fmaf(x0, BF_LO(q.z), acc[4]); acc[5] = fmaf(x0, BF_HI(q.z), acc[5]);
    acc[6] = fmaf(x0, BF_LO(q.w), acc[6]); acc[7] = fmaf(x0, BF_HI(q.w), acc[7]);
    ssum += x0;
  }
  float inv = 1.f / (ssum + 1e-16f);
  float4 b0 = *(const float4*)(b1 + f0);
  float4 b4 = *(const float4*)(b1 + f0 + 4);
  float o[8];
  o[0] = acc[0] * inv + b0.x; o[1] = acc[1] * inv + b0.y;
  o[2] = acc[2] * inv + b0.z; o[3] = acc[3] * inv + b0.w;
  o[4] = acc[4] * inv + b4.x; o[5] = acc[5] * inv + b4.y;
  o[6] = acc[6] * inv + b4.z; o[7] = acc[7] * inv + b4.w;
  float4 w0 = {o[0], o[1], o[2], o[3]};
  float4 w1 = {o[4], o[5], o[6], o[7]};
  *(float4*)(h1b + (size_t)n * F1 + f0) = w0;
  *(float4*)(h1b + (size_t)n * F1 + f0 + 4) = w1;
#pragma unroll
  for (int j = 0; j < 8; ++j) {
    atomicAdd(&bns[f0 + j], o[j]);
    atomicAdd(&bnq[f0 + j], o[j] * o[j]);
  }
  __syncthreads();
  if (t < 128) {
    atomicAdd(bnsum + t, bns[t]);
    atomicAdd(bnsq + t, bnq[t]);
  }
}

// ---------------- BN stats -> per-feature scale/shift ----------------
__global__ void bnstats_kernel(const float* __restrict__ bnsum, const float* __restrict__ bnsq,
                               const float* __restrict__ gamma, const float* __restrict__ beta,
                               float* __restrict__ scale, float* __restrict__ shift) {
  int f = threadIdx.x;
  if (f < 128) {
    const float invN = 1.f / (float)NN;
    float mu = bnsum[f] * invN;
    float var = bnsq[f] * invN - mu * mu;
    float sc = gamma[f] * rsqrtf(var + 1e-5f);
    scale[f] = sc;
    shift[f] = beta[f] - mu * sc;
  }
}

// -- GEMM2 (BN+ELU fused on A-load, a2 dots fused): h2bf[N,64] bf16 padded --
__global__ __launch_bounds__(256) void gemm2_kernel(const float* __restrict__ hpre,
                                                    const float* __restrict__ W2,
                                                    const float* __restrict__ scale,
                                                    const float* __restrict__ shift,
                                                    const float* __restrict__ att_src2,
                                                    const float* __restrict__ att_dst2,
                                                    u16* __restrict__ h2bf,
                                                    float* __restrict__ a_src2,
                                                    float* __restrict__ a_dst2) {
  __shared__ float Wlds[128 * 40];
  __shared__ float Alds[16 * 128];
  __shared__ float sc[128], sh[128];
  int t = threadIdx.x;
  for (int i = t; i < 128 * 40; i += 256) Wlds[i] = W2[i];
  if (t < 128) { sc[t] = scale[t]; sh[t] = shift[t]; }
  int tr = t >> 3;
  int tc = t & 7;
  float as5[5], ad5[5];
#pragma unroll
  for (int j = 0; j < 5; ++j) { as5[j] = att_src2[tc * 5 + j]; ad5[j] = att_dst2[tc * 5 + j]; }
  int n0 = blockIdx.x * 128;
  int lrow = t >> 1;
  int lkk = (t & 1) * 8;
  float acc[4][5];
#pragma unroll
  for (int i = 0; i < 4; ++i)
#pragma unroll
    for (int j = 0; j < 5; ++j) acc[i][j] = 0.f;

  for (int k0 = 0; k0 < F1; k0 += 16) {
    float av[8];
    int gn = n0 + lrow;
    if (gn < NN) {
      float4 v0 = *(const float4*)(hpre + (size_t)gn * F1 + k0 + lkk);
      float4 v1 = *(const float4*)(hpre + (size_t)gn * F1 + k0 + lkk + 4);
      av[0] = v0.x; av[1] = v0.y; av[2] = v0.z; av[3] = v0.w;
      av[4] = v1.x; av[5] = v1.y; av[6] = v1.z; av[7] = v1.w;
    } else {
#pragma unroll
      for (int j = 0; j < 8; ++j) av[j] = 0.f;
    }
    __syncthreads();
#pragma unroll
    for (int j = 0; j < 8; ++j) {
      int kg = k0 + lkk + j;
      float a = av[j] * sc[kg] + sh[kg];
      a = a > 0.f ? a : (__expf(a) - 1.f);
      Alds[(lkk + j) * 128 + lrow] = a;
    }
    __syncthreads();
#pragma unroll
    for (int k = 0; k < 16; ++k) {
      float4 a4 = *(const float4*)(Alds + k * 128 + tr * 4);
      float aa[4] = {a4.x, a4.y, a4.z, a4.w};
      float w[5];
#pragma unroll
      for (int j = 0; j < 5; ++j) w[j] = Wlds[(k0 + k) * 40 + tc * 5 + j];
#pragma unroll
      for (int i = 0; i < 4; ++i)
#pragma unroll
        for (int j = 0; j < 5; ++j) acc[i][j] = fmaf(aa[i], w[j], acc[i][j]);
    }
  }
#pragma unroll
  for (int i = 0; i < 4; ++i) {
    int gn = n0 + tr * 4 + i;
    if (gn < NN) {
#pragma unroll
      for (int j = 0; j < 5; ++j)
        h2bf[(size_t)gn * 64 + tc * 5 + j] = (u16)f2bf(acc[i][j]);
      if (tc < 6) {
        uint2 z = {0u, 0u};
        *(uint2*)((u32*)h2bf + (size_t)gn * 32 + 20 + 2 * tc) = z;  // pad elems 40..63
      }
    }
  }
  // fused a2 dots: reduce across the 8 lanes (tc) sharing a row
#pragma unroll
  for (int i = 0; i < 4; ++i) {
    float ps = 0.f, pd = 0.f;
#pragma unroll
    for (int j = 0; j < 5; ++j) { ps += acc[i][j] * as5[j]; pd += acc[i][j] * ad5[j]; }
#pragma unroll
    for (int off = 1; off < 8; off <<= 1) {
      ps += __shfl_xor(ps, off);
      pd += __shfl_xor(pd, off);
    }
    if (tc == 0) {
      int gn = n0 + tr * 4 + i;
      if (gn < NN) { a_src2[gn] = ps; a_dst2[gn] = pd; }
    }
  }
}

// ------- gather layer2: 8 lanes/node, uint4 rows, int4 csr; writes output -------
__global__ __launch_bounds__(256) void gather2_kernel(const int* __restrict__ rowstart,
                                                      const int* __restrict__ csr_src,
                                                      const float* __restrict__ a_src,
                                                      const float* __restrict__ a_dst,
                                                      const u32* __restrict__ h2bf,
                                                      const float* __restrict__ b2,
                                                      float* __restrict__ out) {
  int t = threadIdx.x;
  int n = blockIdx.x * 32 + (t >> 3);
  if (n >= NN) return;
  int l = t & 7;
  float adst = a_dst[n];
  float acc[8] = {0.f, 0.f, 0.f, 0.f, 0.f, 0.f, 0.f, 0.f};
  float ssum = 0.f;
  int beg = rowstart[n], end = rowstart[n + 1];
  int i = beg;
  for (; i < end && (i & 3); ++i) {
    int s0 = csr_src[i];
    float e0 = a_src[s0] + adst;
    e0 = e0 > 0.f ? e0 : 0.2f * e0;
    float x0 = __expf(e0);
    uint4 q = *(const uint4*)(h2bf + (size_t)s0 * 32 + l * 4);
    acc[0] = fmaf(x0, BF_LO(q.x), acc[0]); acc[1] = fmaf(x0, BF_HI(q.x), acc[1]);
    acc[2] = fmaf(x0, BF_LO(q.y), acc[2]); acc[3] = fmaf(x0, BF_HI(q.y), acc[3]);
    acc[4] = fmaf(x0, BF_LO(q.z), acc[4]); acc[5] = fmaf(x0, BF_HI(q.z), acc[5]);
    acc[6] = fmaf(x0, BF_LO(q.w), acc[6]); acc[7] = fmaf(x0, BF_HI(q.w), acc[7]);
    ssum += x0;
  }
  for (; i + 3 < end; i += 4) {
    int4 s4 = *(const int4*)(csr_src + i);
    float e0 = a_src[s4.x] + adst;
    float e1 = a_src[s4.y] + adst;
    float e2 = a_src[s4.z] + adst;
    float e3 = a_src[s4.w] + adst;
    uint4 q0 = *(const uint4*)(h2bf + (size_t)s4.x * 32 + l * 4);
    uint4 q1 = *(const uint4*)(h2bf + (size_t)s4.y * 32 + l * 4);
    uint4 q2 = *(const uint4*)(h2bf + (size_t)s4.z * 32 + l * 4);
    uint4 q3 = *(const uint4*)(h2bf + (size_t)s4.w * 32 + l * 4);
    e0 = e0 > 0.f ? e0 : 0.2f * e0;  float x0 = __expf(e0);
    e1 = e1 > 0.f ? e1 : 0.2f * e1;  float x1 = __expf(e1);
    e2 = e2 > 0.f ? e2 : 0.2f * e2;  float x2 = __expf(e2);
    e3 = e3 > 0.f ? e3 : 0.2f * e3;  float x3 = __expf(e3);
    acc[0] = fmaf(x0, BF_LO(q0.x), acc[0]); acc[1] = fmaf(x0, BF_HI(q0.x), acc[1]);
    acc[2] = fmaf(x0, BF_LO(q0.y), acc[2]); acc[3] = fmaf(x0, BF_HI(q0.y), acc[3]);
    acc[4] = fmaf(x0, BF_LO(q0.z), acc[4]); acc[5] = fmaf(x0, BF_HI(q0.z), acc[5]);
    acc[6] = fmaf(x0, BF_LO(q0.w), acc[6]); acc[7] = fmaf(x0, BF_HI(q0.w), acc[7]);
    acc[0] = fmaf(x1, BF_LO(q1.x), acc[0]); acc[1] = fmaf(x1, BF_HI(q1.x), acc[1]);
    acc[2] = fmaf(x1, BF_LO(q1.y), acc[2]); acc[3] = fmaf(x1, BF_HI(q1.y), acc[3]);
    acc[4] = fmaf(x1, BF_LO(q1.z), acc[4]); acc[5] = fmaf(x1, BF_HI(q1.z), acc[5]);
    acc[6] = fmaf(x1, BF_LO(q1.w), acc[6]); acc[7] = fmaf(x1, BF_HI(q1.w), acc[7]);
    acc[0] = fmaf(x2, BF_LO(q2.x), acc[0]); acc[1] = fmaf(x2, BF_HI(q2.x), acc[1]);
    acc[2] = fmaf(x2, BF_LO(q2.y), acc[2]); acc[3] = fmaf(x2, BF_HI(q2.y), acc[3]);
    acc[4] = fmaf(x2, BF_LO(q2.z), acc[4]); acc[5] = fmaf(x2, BF_HI(q2.z), acc[5]);
    acc[6] = fmaf(x2, BF_LO(q2.w), acc[6]); acc[7] = fmaf(x2, BF_HI(q2.w), acc[7]);
    acc[0] = fmaf(x3, BF_LO(q3.x), acc[0]); acc[1] = fmaf(x3, BF_HI(q3.x), acc[1]);
    acc[2] = fmaf(x3, BF_LO(q3.y), acc[2]); acc[3] = fmaf(x3, BF_HI(q3.y), acc[3]);
    acc[4] = fmaf(x3, BF_LO(q3.z), acc[4]); acc[5] = fmaf(x3, BF_HI(q3.z), acc[5]);
    acc[6] = fmaf(x3, BF_LO(q3.w), acc[6]); acc[7] = fmaf(x3, BF_HI(q3.w), acc[7]);
    ssum += x0 + x1 + x2 + x3;
  }
  for (; i < end; ++i) {
    int s0 = csr_src[i];
    float e0 = a_src[s0] + adst;
    e0 = e0 > 0.f ? e0 : 0.2f * e0;
    float x0 = __expf(e0);
    uint4 q = *(const uint4*)(h2bf + (size_t)s0 * 32 + l * 4);
    acc[0] = fmaf(x0, BF_LO(q.x), acc[0]); acc[1] = fmaf(x0, BF_HI(q.x), acc[1]);
    acc[2] = fmaf(x0, BF_LO(q.y), acc[2]); acc[3] = fmaf(x0, BF_HI(q.y), acc[3]);
    acc[4] = fmaf(x0, BF_LO(q.z), acc[4]); acc[5] = fmaf(x0, BF_HI(q.z), acc[5]);
    acc[6] = fmaf(x0, BF_LO(q.w), acc[6]); acc[7] = fmaf(x0, BF_HI(q.w), acc[7]);
    ssum += x0;
  }
  float inv = 1.f / (ssum + 1e-16f);
  if (l < 5) {
    float* op = out + (size_t)n * F2 + l * 8;
#pragma unroll
    for (int j = 0; j < 8; ++j) op[j] = acc[j] * inv + b2[l * 8 + j];
  }
}

extern "C" void kernel_launch(void* const* d_in, const int* in_sizes, int n_in,
                              void* d_out, int out_size, void* d_ws, size_t ws_size,
                              hipStream_t stream) {
  const float* x        = (const float*)d_in[0];
  const int*   ei       = (const int*)d_in[1];
  const float* W1       = (const float*)d_in[2];
  const float* att_src1 = (const float*)d_in[3];
  const float* att_dst1 = (const float*)d_in[4];
  const float* b1       = (const float*)d_in[5];
  const float* gamma    = (const float*)d_in[6];
  const float* beta     = (const float*)d_in[7];
  const float* W2       = (const float*)d_in[8];
  const float* att_src2 = (const float*)d_in[9];
  const float* att_dst2 = (const float*)d_in[10];
  const float* b2       = (const float*)d_in[11];
  float* out = (float*)d_out;

  // ---- workspace layout (all element counts multiples of 4 -> 16B aligned) ----
  int* deg = (int*)d_ws;                       // 50048 (zeroed)
  float* bnsum = (float*)(deg + 50048);        // 128   (zeroed)
  float* bnsq  = bnsum + 128;                  // 128   (zeroed)
  int* rowstart = (int*)(bnsq + 128);          // 50004
  int* cursor   = rowstart + 50004;            // 50000
  int* csr_src  = cursor + 50000;              // 850000
  u32* h1bf     = (u32*)(csr_src + 850000);    // 50000*64 = 3,200,000 u32 (bf16 x2)
  float* h1b    = (float*)(h1bf + 3200000);    // 6,400,000
  u32* h2bf     = (u32*)(h1b + 6400000);       // 50000*32 = 1,600,000 u32 (bf16 x2)
  float* a_src1 = (float*)(h2bf + 1600000);    // 200000
  float* a_dst1 = a_src1 + 200000;             // 200000
  float* a_src2 = a_dst1 + 200000;             // 50000
  float* a_dst2 = a_src2 + 50000;              // 50000
  float* scale  = a_dst2 + 50000;              // 128
  float* shift  = scale + 128;                 // 128

  hipMemsetAsync(deg, 0, (50048 + 256) * sizeof(int), stream);

  deg_kernel<<<(ETOT + 255) / 256, 256, 0, stream>>>(ei, deg);
  scan_kernel<<<1, 1024, 0, stream>>>(deg, rowstart, cursor);
  fill_kernel<<<(ETOT + 255) / 256, 256, 0, stream>>>(ei, cursor, csr_src);

  gemm1_kernel<<<(NN + 63) / 64, 256, 0, stream>>>(x, W1, att_src1, att_dst1,
                                                   h1bf, a_src1, a_dst1);
  gather1_kernel<<<NN / 16, 256, 0, stream>>>(rowstart, csr_src, a_src1, a_dst1,
                                              h1bf, b1, h1b, bnsum, bnsq);
  bnstats_kernel<<<1, 128, 0, stream>>>(bnsum, bnsq, gamma, beta, scale, shift);
  gemm2_kernel<<<(NN + 127) / 128, 256, 0, stream>>>(h1b, W2, scale, shift,
                                                     att_src2, att_dst2,
                                                     (u16*)h2bf, a_src2, a_dst2);
  gather2_kernel<<<(NN + 31) / 32, 256, 0, stream>>>(rowstart, csr_src, a_src2, a_dst2,
                                                     h2bf, b2, out);
}